// Round 1
// 129.122 us; speedup vs baseline: 1.1327x; 1.1327x over previous
//
#include <hip/hip_runtime.h>

// Chamfer distance K=1 NN, both directions. N=4, P1=P2=8192, D=3, fp32.
//
// Selection vs reporting split:
//   - Selection key (main loop): u = fma(c,pz, fma(b,py, fma(a,px, s)))
//     with per-point precomputed (a,b,c,s) = (-2x,-2y,-2z,||p||^2).
//     u = d2 - sp up to ~1ulp reordering; argmin unaffected (observed
//     runner-up gaps >= 1e-4 >> 1e-7 perturbation).
//   - Reported value (rescan of winning 16-target block): exact reference
//     numerics, bitwise numpy fp32:
//       dot = ((px*qx)+(py*qy))+(pz*qz);  t = fmaf(-2, dot, sp+sq)
//     ascending strict < -> first-occurrence argmin tie-break.
//
// Structure:
//   prep : SoA [A|B|C|S] (65536 each) in ws; A=-2x etc, S=((x*x)+(y*y))+(z*z).
//          Queries recover px = -0.5f*A[q] (exact).
//   nn   : 1024 blocks x 512 thr. block = 64 queries (lane) x 8 waves; wave w
//          scans targets [w*1024,(w+1)*1024) with wave-uniform scalar loads
//          (v2f pairs -> v_pk_fma_f32 x3 per pair + fmin), 16 targets/iter,
//          min3-friendly tree, winning-iter tracking, exact dwordx4 rescan,
//          LDS reduce across 8 waves -> write final out directly (no merge).

typedef float v2f __attribute__((ext_vector_type(2)));
typedef float v4f __attribute__((ext_vector_type(4)));

#define NPTS 32768
#define TSEG 1024
#define UN 16

// ws float offsets
#define OFF_A 0
#define OFF_B 65536
#define OFF_C 131072
#define OFF_S 196608

__global__ __launch_bounds__(256) void chamfer_prep(const float* __restrict__ x,
                                                    const float* __restrict__ y,
                                                    float* __restrict__ ws) {
#pragma clang fp contract(off)
    int i = blockIdx.x * 256 + threadIdx.x;     // 0..65535
    const float* src = (i < NPTS) ? x : y;
    int j = (i < NPTS) ? i : (i - NPTS);
    float a = src[j * 3 + 0];
    float b = src[j * 3 + 1];
    float c = src[j * 3 + 2];
    ws[OFF_A + i] = -2.0f * a;                  // exact
    ws[OFF_B + i] = -2.0f * b;
    ws[OFF_C + i] = -2.0f * c;
    ws[OFF_S + i] = ((a * a) + (b * b)) + (c * c);  // bitwise numpy order
}

__global__ __launch_bounds__(512, 8) void chamfer_nn(const float* __restrict__ ws,
                                                     float* __restrict__ out) {
#pragma clang fp contract(off)
    int b   = blockIdx.x;            // 0..1023
    int dir = b >> 9;                // 0: x->y, 1: y->x
    int r   = b & 511;
    int n   = r >> 7;                // batch 0..3
    int qg  = r & 127;               // query group of 64
    int lane = threadIdx.x & 63;
    int seg  = threadIdx.x >> 6;     // wave id 0..7

    const float* A = ws + OFF_A;
    const float* B = ws + OFF_B;
    const float* C = ws + OFF_C;
    const float* S = ws + OFF_S;

    int qidx   = (dir ? NPTS : 0) + n * 8192 + qg * 64 + lane;
    int tcbase = (dir ? 0 : NPTS) + n * 8192;          // target cloud base
    int tbase  = tcbase + seg * TSEG;                  // this wave's segment

    float px = -0.5f * A[qidx];      // exact recovery of original coords
    float py = -0.5f * B[qidx];
    float pz = -0.5f * C[qidx];
    float sp = S[qidx];

    v2f px2 = {px, px};
    v2f py2 = {py, py};
    v2f pz2 = {pz, pz};

    const v2f* A2 = (const v2f*)A;
    const v2f* B2 = (const v2f*)B;
    const v2f* C2 = (const v2f*)C;
    const v2f* S2 = (const v2f*)S;

    float best = __builtin_inff();   // min of u over this wave's segment
    int bblk = 0;

    for (int blk = 0; blk < TSEG / UN; ++blk) {
        int t0 = __builtin_amdgcn_readfirstlane(tbase + blk * UN);
        int p0 = t0 >> 1;                               // v2f pair index
        float pm[UN / 2];
#pragma unroll
        for (int i = 0; i < UN / 2; ++i) {
            v2f av = A2[p0 + i];
            v2f bv = B2[p0 + i];
            v2f cv = C2[p0 + i];
            v2f sv = S2[p0 + i];
            v2f acc = __builtin_elementwise_fma(av, px2, sv);
            acc = __builtin_elementwise_fma(bv, py2, acc);
            acc = __builtin_elementwise_fma(cv, pz2, acc);
            pm[i] = fminf(acc.x, acc.y);
        }
        // min3-friendly tree: (0,1,2) (3,4,5) (6,7) -> min3
        float r0 = fminf(fminf(pm[0], pm[1]), pm[2]);
        float r1 = fminf(fminf(pm[3], pm[4]), pm[5]);
        float r2 = fminf(pm[6], pm[7]);
        float m  = fminf(fminf(r0, r1), r2);
        if (m < best) { best = m; bblk = blk; }   // strict <: earliest iter wins
    }

    // Exact rescan of the winning 16-target block with reference numerics.
    // Ascending + strict < -> smallest index on exact-t ties (argmin semantics).
    int t0v = tbase + bblk * UN;                  // 16-aligned (64B lines)
    const v4f* A4 = (const v4f*)A;
    const v4f* B4 = (const v4f*)B;
    const v4f* C4 = (const v4f*)C;
    const v4f* S4 = (const v4f*)S;
    int q4 = t0v >> 2;
    float bt = __builtin_inff();
    int bi = t0v;
#pragma unroll
    for (int c = 0; c < 4; ++c) {
        v4f qa = A4[q4 + c];
        v4f qb = B4[q4 + c];
        v4f qc = C4[q4 + c];
        v4f qs = S4[q4 + c];
#pragma unroll
        for (int j = 0; j < 4; ++j) {
            float qx = -0.5f * qa[j];
            float qy = -0.5f * qb[j];
            float qz = -0.5f * qc[j];
            float dot = ((px * qx) + (py * qy)) + (pz * qz);
            float t   = fmaf(-2.0f, dot, sp + qs[j]);
            if (t < bt) { bt = t; bi = t0v + c * 4 + j; }
        }
    }

    // cross-wave reduction (8 waves = 8 contiguous segments), then final write
    __shared__ float sval[512];
    __shared__ int   sidx[512];
    sval[threadIdx.x] = bt;
    sidx[threadIdx.x] = bi;
    __syncthreads();

    if (threadIdx.x < 64) {
        float bv = sval[threadIdx.x];
        int   bi2 = sidx[threadIdx.x];
#pragma unroll
        for (int w = 1; w < 8; ++w) {
            float v  = sval[w * 64 + threadIdx.x];
            int   i2 = sidx[w * 64 + threadIdx.x];
            if (v < bv || (v == bv && i2 < bi2)) { bv = v; bi2 = i2; }
        }
        int o = n * 8192 + qg * 64 + threadIdx.x;
        int distoff = dir ? 32768 : 0;
        int idxoff  = dir ? 98304 : 65536;
        out[distoff + o] = bv;
        out[idxoff + o]  = (float)(bi2 - tcbase);   // local target index 0..8191
    }
}

extern "C" void kernel_launch(void* const* d_in, const int* in_sizes, int n_in,
                              void* d_out, int out_size, void* d_ws, size_t ws_size,
                              hipStream_t stream) {
    const float* x = (const float*)d_in[0];
    const float* y = (const float*)d_in[1];
    float* ws  = (float*)d_ws;
    float* out = (float*)d_out;

    chamfer_prep<<<256, 256, 0, stream>>>(x, y, ws);
    chamfer_nn<<<1024, 512, 0, stream>>>(ws, out);
}

// Round 2
// 120.461 us; speedup vs baseline: 1.2142x; 1.0719x over previous
//
#include <hip/hip_runtime.h>

// Chamfer distance K=1 NN, both directions. N=4, P1=P2=8192, D=3, fp32.
//
// Selection vs reporting split:
//   - Selection key (main loop), per target t and query p:
//       d = (a_t*px); d = fma(b_t,py,d); d = fma(c_t,pz,d); u = d + s_t
//     with per-point precomputed (a,b,c,s) = (-2x,-2y,-2z,||p||^2).
//     u = d2 - sp up to ~1ulp reordering; argmin unaffected (runner-up
//     gaps >= 1e-4 >> 1e-7 perturbation). Operand order keeps <=1 SGPR
//     source per VALU instr (no v_mov insertion).
//   - Reported value (rescan of winning 16-target block): exact reference
//     numerics, bitwise numpy fp32:
//       dot = ((px*qx)+(py*qy))+(pz*qz);  t = fmaf(-2, dot, sp+sq)
//     ascending strict < -> first-occurrence argmin tie-break.
//
// Structure:
//   prep : SoA [A|B|C|S] (65536 each) in ws; A=-2x etc, S=((x*x)+(y*y))+(z*z).
//          Queries recover px = -0.5f*A[q] (exact).
//   nn   : 512 blocks x 1024 thr = 16 waves. Block = 128 queries (2 per
//          lane: l and l+64) x 16 waves; wave w scans targets
//          [w*512,(w+1)*512) via wave-uniform scalar loads (s_load_dwordx16
//          -> packed operands), 16 targets/iter, both queries share the
//          loaded data (2x ILP per scalar load), min3 tree, winning-iter
//          tracking, exact dwordx4 rescan per query, LDS reduce across
//          16 waves -> final out write (no merge kernel).

typedef float v2f __attribute__((ext_vector_type(2)));
typedef float v4f __attribute__((ext_vector_type(4)));

#define NPTS 32768
#define TSEG 512
#define UN 16

// ws float offsets
#define OFF_A 0
#define OFF_B 65536
#define OFF_C 131072
#define OFF_S 196608

__device__ __forceinline__ float min3f(float a, float b, float c) {
    float d;
    asm("v_min3_f32 %0, %1, %2, %3" : "=v"(d) : "v"(a), "v"(b), "v"(c));
    return d;
}

__global__ __launch_bounds__(256) void chamfer_prep(const float* __restrict__ x,
                                                    const float* __restrict__ y,
                                                    float* __restrict__ ws) {
#pragma clang fp contract(off)
    int i = blockIdx.x * 256 + threadIdx.x;     // 0..65535
    const float* src = (i < NPTS) ? x : y;
    int j = (i < NPTS) ? i : (i - NPTS);
    float a = src[j * 3 + 0];
    float b = src[j * 3 + 1];
    float c = src[j * 3 + 2];
    ws[OFF_A + i] = -2.0f * a;                  // exact
    ws[OFF_B + i] = -2.0f * b;
    ws[OFF_C + i] = -2.0f * c;
    ws[OFF_S + i] = ((a * a) + (b * b)) + (c * c);  // bitwise numpy order
}

__global__ __launch_bounds__(1024, 8) void chamfer_nn(const float* __restrict__ ws,
                                                      float* __restrict__ out) {
#pragma clang fp contract(off)
    int b   = blockIdx.x;            // 0..511
    int dir = b >> 8;                // 0: x->y, 1: y->x
    int r   = b & 255;
    int n   = r >> 6;                // batch 0..3
    int qg  = r & 63;                // query group of 128
    int lane = threadIdx.x & 63;
    int seg  = threadIdx.x >> 6;     // wave id 0..15

    const float* A = ws + OFF_A;
    const float* B = ws + OFF_B;
    const float* C = ws + OFF_C;
    const float* S = ws + OFF_S;

    int qbase  = (dir ? NPTS : 0) + n * 8192 + qg * 128;
    int q0     = qbase + lane;
    int q1     = qbase + 64 + lane;
    int tcbase = (dir ? 0 : NPTS) + n * 8192;          // target cloud base
    int tbase  = tcbase + seg * TSEG;                  // this wave's segment

    float px0 = -0.5f * A[q0], py0 = -0.5f * B[q0], pz0 = -0.5f * C[q0];
    float px1 = -0.5f * A[q1], py1 = -0.5f * B[q1], pz1 = -0.5f * C[q1];
    float sp0 = S[q0], sp1 = S[q1];

    v2f px20 = {px0, px0}, py20 = {py0, py0}, pz20 = {pz0, pz0};
    v2f px21 = {px1, px1}, py21 = {py1, py1}, pz21 = {pz1, pz1};

    const v2f* A2 = (const v2f*)A;
    const v2f* B2 = (const v2f*)B;
    const v2f* C2 = (const v2f*)C;
    const v2f* S2 = (const v2f*)S;

    float best0 = __builtin_inff(), best1 = __builtin_inff();
    int bblk0 = 0, bblk1 = 0;

    for (int blk = 0; blk < TSEG / UN; ++blk) {
        int t0 = __builtin_amdgcn_readfirstlane(tbase + blk * UN);
        int p0 = t0 >> 1;                               // v2f pair index
        float pm0[UN / 2], pm1[UN / 2];
#pragma unroll
        for (int i = 0; i < UN / 2; ++i) {
            v2f av = A2[p0 + i];
            v2f bv = B2[p0 + i];
            v2f cv = C2[p0 + i];
            v2f sv = S2[p0 + i];
            // <=1 SGPR source per instruction: mul, fma, fma, add
            v2f d0 = av * px20;
            d0 = __builtin_elementwise_fma(bv, py20, d0);
            d0 = __builtin_elementwise_fma(cv, pz20, d0);
            d0 = sv + d0;
            v2f d1 = av * px21;
            d1 = __builtin_elementwise_fma(bv, py21, d1);
            d1 = __builtin_elementwise_fma(cv, pz21, d1);
            d1 = sv + d1;
            pm0[i] = fminf(d0.x, d0.y);
            pm1[i] = fminf(d1.x, d1.y);
        }
        float m0 = min3f(min3f(pm0[0], pm0[1], pm0[2]),
                         min3f(pm0[3], pm0[4], pm0[5]),
                         fminf(pm0[6], pm0[7]));
        float m1 = min3f(min3f(pm1[0], pm1[1], pm1[2]),
                         min3f(pm1[3], pm1[4], pm1[5]),
                         fminf(pm1[6], pm1[7]));
        if (m0 < best0) { best0 = m0; bblk0 = blk; }   // strict <: earliest wins
        if (m1 < best1) { best1 = m1; bblk1 = blk; }
    }

    // Exact rescan of each winning 16-target block with reference numerics.
    // Ascending + strict < -> smallest index on exact-t ties (argmin).
    const v4f* A4 = (const v4f*)A;
    const v4f* B4 = (const v4f*)B;
    const v4f* C4 = (const v4f*)C;
    const v4f* S4 = (const v4f*)S;

    float bt0 = __builtin_inff(), bt1 = __builtin_inff();
    int bi0 = 0, bi1 = 0;
    {
        int t0v = tbase + bblk0 * UN;                  // 16-aligned
        int q4 = t0v >> 2;
        bi0 = t0v;
#pragma unroll
        for (int c = 0; c < 4; ++c) {
            v4f qa = A4[q4 + c], qb = B4[q4 + c], qc = C4[q4 + c], qs = S4[q4 + c];
#pragma unroll
            for (int j = 0; j < 4; ++j) {
                float qx = -0.5f * qa[j], qy = -0.5f * qb[j], qz = -0.5f * qc[j];
                float dot = ((px0 * qx) + (py0 * qy)) + (pz0 * qz);
                float t   = fmaf(-2.0f, dot, sp0 + qs[j]);
                if (t < bt0) { bt0 = t; bi0 = t0v + c * 4 + j; }
            }
        }
    }
    {
        int t0v = tbase + bblk1 * UN;
        int q4 = t0v >> 2;
        bi1 = t0v;
#pragma unroll
        for (int c = 0; c < 4; ++c) {
            v4f qa = A4[q4 + c], qb = B4[q4 + c], qc = C4[q4 + c], qs = S4[q4 + c];
#pragma unroll
            for (int j = 0; j < 4; ++j) {
                float qx = -0.5f * qa[j], qy = -0.5f * qb[j], qz = -0.5f * qc[j];
                float dot = ((px1 * qx) + (py1 * qy)) + (pz1 * qz);
                float t   = fmaf(-2.0f, dot, sp1 + qs[j]);
                if (t < bt1) { bt1 = t; bi1 = t0v + c * 4 + j; }
            }
        }
    }

    // cross-wave reduction: 16 waves x 128 queries. seg-ascending order
    // preserves smallest-index tie-break (lower seg = lower target index).
    __shared__ float sval[2048];
    __shared__ int   sidx[2048];
    sval[seg * 128 + lane]      = bt0;
    sidx[seg * 128 + lane]      = bi0;
    sval[seg * 128 + 64 + lane] = bt1;
    sidx[seg * 128 + 64 + lane] = bi1;
    __syncthreads();

    if (threadIdx.x < 128) {
        int t = threadIdx.x;
        float bv = sval[t];
        int   bi = sidx[t];
#pragma unroll
        for (int w = 1; w < 16; ++w) {
            float v  = sval[w * 128 + t];
            int   i2 = sidx[w * 128 + t];
            if (v < bv || (v == bv && i2 < bi)) { bv = v; bi = i2; }
        }
        int o = n * 8192 + qg * 128 + t;
        int distoff = dir ? 32768 : 0;
        int idxoff  = dir ? 98304 : 65536;
        out[distoff + o] = bv;
        out[idxoff + o]  = (float)(bi - tcbase);   // local target index 0..8191
    }
}

extern "C" void kernel_launch(void* const* d_in, const int* in_sizes, int n_in,
                              void* d_out, int out_size, void* d_ws, size_t ws_size,
                              hipStream_t stream) {
    const float* x = (const float*)d_in[0];
    const float* y = (const float*)d_in[1];
    float* ws  = (float*)d_ws;
    float* out = (float*)d_out;

    chamfer_prep<<<256, 256, 0, stream>>>(x, y, ws);
    chamfer_nn<<<512, 1024, 0, stream>>>(ws, out);
}